// Round 6
// baseline (476.662 us; speedup 1.0000x reference)
//
#include <hip/hip_runtime.h>
#include <math.h>

// Sparsemax over rows of a (16384 x 4096) float32 matrix — two-phase split.
//
// Phase 1 (tau_kernel, read-only): one wave per row. Bound tau >= max-1 =>
// support in {x > max-1} (~14-60 elems). Gather candidates into a per-wave
// LDS segment (no barriers, same-wave LDS ordering + lgkmcnt), solve tau
// exactly with the one-pass rank formula in raw space:
//   C_i = #{j: y_j >= y_i}, S_i = sum{y_j >= y_i};
//   k = max C_i over lanes with 1 + C_i*y_i > S_i; tau = (S_i-1)/C_i.
// Fallback (cnt > 128, ~never): in-register per-wave Michelot.
// tau[row] -> d_ws.
//
// Phase 2 (apply_kernel): pure stream out = max(x - tau[row], 0), one float4
// per thread, no reductions, no sync — structurally the fill kernel.
//
// This split discriminates: if the fused ~153us was reduction-serialization,
// the sum of two clean phases beats it; if it was a mixed-stream BW cap, it
// won't.

constexpr int N_COLS = 4096;
constexpr int BLOCK = 256;
constexpr int WAVES = BLOCK / 64;        // 4 rows per block in phase 1
constexpr int CHUNKS = N_COLS / 4 / 64;  // 16 float4 per lane per row
constexpr int CAP = 128;                 // candidate capacity (2 slots/lane)

__global__ __launch_bounds__(BLOCK) void tau_kernel(
    const float* __restrict__ x, float* __restrict__ taus, int nrows) {
  const int w = threadIdx.x >> 6;
  const int lane = threadIdx.x & 63;
  const int row = blockIdx.x * WAVES + w;
  if (row >= nrows) return;
  const float4* x4 = (const float4*)(x + (size_t)row * N_COLS);

  __shared__ float sY[WAVES][CAP];
  __shared__ int sN[WAVES];
  float* ldsY = sY[w];
  if (lane == 0) sN[w] = 0;  // same-wave DS ops are in order vs the atomics

  // ---- issue the whole row's loads (16 KB/wave in flight) ----
  float4 f[CHUNKS];
#pragma unroll
  for (int k = 0; k < CHUNKS; ++k) f[k] = x4[k * 64 + lane];

  // ---- wave max (raw space) ----
  float m = fmaxf(fmaxf(f[0].x, f[0].y), fmaxf(f[0].z, f[0].w));
#pragma unroll
  for (int k = 1; k < CHUNKS; ++k)
    m = fmaxf(m, fmaxf(fmaxf(f[k].x, f[k].y), fmaxf(f[k].z, f[k].w)));
#pragma unroll
  for (int off = 32; off >= 1; off >>= 1) m = fmaxf(m, __shfl_xor(m, off, 64));
  const float thresh = m - 1.0f;

  // ---- gather candidates into this wave's LDS segment ----
#pragma unroll
  for (int k = 0; k < CHUNKS; ++k) {
    if (f[k].x > thresh) { int i = atomicAdd(&sN[w], 1); if (i < CAP) ldsY[i] = f[k].x; }
    if (f[k].y > thresh) { int i = atomicAdd(&sN[w], 1); if (i < CAP) ldsY[i] = f[k].y; }
    if (f[k].z > thresh) { int i = atomicAdd(&sN[w], 1); if (i < CAP) ldsY[i] = f[k].z; }
    if (f[k].w > thresh) { int i = atomicAdd(&sN[w], 1); if (i < CAP) ldsY[i] = f[k].w; }
  }
  __asm__ volatile("s_waitcnt lgkmcnt(0)" ::: "memory");
  const int cnt = sN[w];  // wave-uniform

  float tau;
  if (cnt <= CAP) {
    // ---- exact one-pass rank formula, 2 candidate slots per lane ----
    const bool in0 = lane < cnt, in1 = lane + 64 < cnt;
    float y0 = in0 ? ldsY[lane] : 0.f;
    float y1 = in1 ? ldsY[lane + 64] : 0.f;
    float S0 = 0.f, C0 = 0.f, S1 = 0.f, C1 = 0.f;
    for (int j = 0; j < cnt; ++j) {  // uniform trip; ldsY[j] is a broadcast
      float yj = ldsY[j];
      if (yj >= y0) { S0 += yj; C0 += 1.f; }
      if (yj >= y1) { S1 += yj; C1 += 1.f; }
    }
    bool ok0 = in0 && (1.f + C0 * y0 > S0);
    bool ok1 = in1 && (1.f + C1 * y1 > S1);
    float bc = ok0 ? C0 : 0.f;
    float bt = ok0 ? (S0 - 1.f) / C0 : 0.f;
    if (ok1 && C1 > bc) { bc = C1; bt = (S1 - 1.f) / C1; }
#pragma unroll
    for (int off = 32; off >= 1; off >>= 1) {
      float oc = __shfl_xor(bc, off, 64);
      float ot = __shfl_xor(bt, off, 64);
      if (oc > bc) { bc = oc; bt = ot; }
    }
    tau = bt;  // uniform (k = max C is unique)
  } else {
    // ---- fallback (~never): in-register per-wave Michelot ----
    tau = thresh;
    int prev = -1;
    for (int it = 0; it < 32; ++it) {
      float S = 0.f, C = 0.f;
#pragma unroll
      for (int k = 0; k < CHUNKS; ++k) {
        if (f[k].x > tau) { S += f[k].x; C += 1.f; }
        if (f[k].y > tau) { S += f[k].y; C += 1.f; }
        if (f[k].z > tau) { S += f[k].z; C += 1.f; }
        if (f[k].w > tau) { S += f[k].w; C += 1.f; }
      }
#pragma unroll
      for (int off = 32; off >= 1; off >>= 1) {
        S += __shfl_xor(S, off, 64);
        C += __shfl_xor(C, off, 64);
      }
      int ci = (int)C;
      tau = (S - 1.f) / C;
      if (ci == prev) break;
      prev = ci;
    }
  }
  if (lane == 0) taus[row] = tau;
}

// ---- Phase 2: pure stream, one float4 per thread ----
__global__ __launch_bounds__(BLOCK) void apply_kernel(
    const float* __restrict__ x, const float* __restrict__ taus,
    float* __restrict__ out) {
  const size_t g = (size_t)blockIdx.x * BLOCK + threadIdx.x;  // float4 index
  const int row = (int)(g >> 10);  // 1024 float4 per row; wave-uniform
  const float t = taus[row];
  const float4 f = ((const float4*)x)[g];
  float4 r;
  r.x = fmaxf(f.x - t, 0.f);
  r.y = fmaxf(f.y - t, 0.f);
  r.z = fmaxf(f.z - t, 0.f);
  r.w = fmaxf(f.w - t, 0.f);
  ((float4*)out)[g] = r;
}

// ---- Fallback fused kernel (only if ws is too small for taus) ----
__global__ __launch_bounds__(BLOCK) void fused_kernel(
    const float* __restrict__ x, float* __restrict__ out) {
  const int row = blockIdx.x;
  const float4* x4 = (const float4*)(x + (size_t)row * N_COLS);
  float4* o4 = (float4*)(out + (size_t)row * N_COLS);
  const int t = threadIdx.x;
  const int wave = t >> 6;
  const int lane = t & 63;
  constexpr int PT = N_COLS / BLOCK;  // 16
  float v[PT];
#pragma unroll
  for (int k = 0; k < PT / 4; ++k) {
    float4 f = x4[t + k * BLOCK];
    v[4 * k + 0] = f.x; v[4 * k + 1] = f.y;
    v[4 * k + 2] = f.z; v[4 * k + 3] = f.w;
  }
  __shared__ float s_red[WAVES];
  __shared__ float s_cand[64];
  __shared__ int s_n;
  float m = v[0];
#pragma unroll
  for (int k = 1; k < PT; ++k) m = fmaxf(m, v[k]);
#pragma unroll
  for (int off = 32; off >= 1; off >>= 1) m = fmaxf(m, __shfl_xor(m, off, 64));
  if (lane == 0) s_red[wave] = m;
  if (t == 0) s_n = 0;
  __syncthreads();
  m = fmaxf(fmaxf(s_red[0], s_red[1]), fmaxf(s_red[2], s_red[3]));
  const float thresh = m - 1.0f;
#pragma unroll
  for (int k = 0; k < PT; ++k) {
    if (v[k] > thresh) {
      int idx = atomicAdd(&s_n, 1);
      if (idx < 64) s_cand[idx] = v[k];
    }
  }
  __syncthreads();
  const int cnt = s_n;
  float tau = thresh;
  if (cnt <= 64) {
    const bool in = lane < cnt;
    float y = in ? s_cand[lane] : 0.0f;
    float S = 0.0f, C = 0.0f;
    for (int j = 0; j < cnt; ++j) {
      float yj = s_cand[j];
      if (yj >= y) { S += yj; C += 1.0f; }
    }
    bool ok = in && (1.0f + C * y > S);
    float bc = ok ? C : 0.0f;
    float bt = ok ? (S - 1.0f) / C : 0.0f;
#pragma unroll
    for (int off = 32; off >= 1; off >>= 1) {
      float oc = __shfl_xor(bc, off, 64);
      float ot = __shfl_xor(bt, off, 64);
      if (oc > bc) { bc = oc; bt = ot; }
    }
    tau = bt;
  } else {
    int prev = -1;
    for (int it = 0; it < 32; ++it) {
      float S = 0.f, C = 0.f;
#pragma unroll
      for (int k = 0; k < PT; ++k)
        if (v[k] > tau) { S += v[k]; C += 1.f; }
#pragma unroll
      for (int off = 32; off >= 1; off >>= 1) {
        S += __shfl_xor(S, off, 64);
        C += __shfl_xor(C, off, 64);
      }
      if (lane == 0) { s_red[wave] = S; s_cand[wave] = C; }
      __syncthreads();
      float SS = s_red[0] + s_red[1] + s_red[2] + s_red[3];
      float CC = s_cand[0] + s_cand[1] + s_cand[2] + s_cand[3];
      __syncthreads();
      int ci = (int)CC;
      tau = (SS - 1.f) / CC;
      if (ci == prev) break;
      prev = ci;
    }
  }
#pragma unroll
  for (int k = 0; k < PT / 4; ++k) {
    float4 r;
    r.x = fmaxf(v[4 * k + 0] - tau, 0.0f);
    r.y = fmaxf(v[4 * k + 1] - tau, 0.0f);
    r.z = fmaxf(v[4 * k + 2] - tau, 0.0f);
    r.w = fmaxf(v[4 * k + 3] - tau, 0.0f);
    o4[t + k * BLOCK] = r;
  }
}

extern "C" void kernel_launch(void* const* d_in, const int* in_sizes, int n_in,
                              void* d_out, int out_size, void* d_ws,
                              size_t ws_size, hipStream_t stream) {
  const float* x = (const float*)d_in[0];
  float* out = (float*)d_out;
  const int rows = in_sizes[0] / N_COLS;  // 16384
  if (ws_size >= (size_t)rows * sizeof(float)) {
    float* taus = (float*)d_ws;
    tau_kernel<<<(rows + WAVES - 1) / WAVES, BLOCK, 0, stream>>>(x, taus, rows);
    const int n4 = rows * (N_COLS / 4);  // total float4 count
    apply_kernel<<<n4 / BLOCK, BLOCK, 0, stream>>>(x, taus, out);
  } else {
    fused_kernel<<<rows, BLOCK, 0, stream>>>(x, out);
  }
}